// Round 7
// baseline (186.239 us; speedup 1.0000x reference)
//
#include <hip/hip_runtime.h>
#include <hip/hip_bf16.h>

// Problem constants: D=1024, H=16, HD=64, B=2, N=1024, rows = B*N = 2048.

typedef __attribute__((ext_vector_type(8))) short bf16x8;
typedef __attribute__((ext_vector_type(4))) float f32x4;

// ws layout (float offsets).
#define OFF_HBF  0                 // h cast to bf16        [2048][1024] us
#define OFF_XBF  1048576           // X (gelu out) bf16     [2048][1024] us
#define OFF_GBF  2097152           // G = W1a(x)Wv bf16     [1024][1024] us
#define OFF_MBF  2621440           // M = Wo(x)fu_W2 bf16   [1024][1024] us
#define OFF_HBAR 3178496           // mean of h over n [2][1024]   (memset w/ bias)
#define OFF_BIAS 3180544           // bias_vec = Wo @ fu_b2 [1024] (memset w/ hbar)
#define OFF_C    3181568           // c vec per (b,head,e) [2][1024]

__device__ __forceinline__ unsigned short f2bf(float f) {
    unsigned int u = __float_as_uint(f);
    u += 0x7fffu + ((u >> 16) & 1u);   // round-to-nearest-even
    return (unsigned short)(u >> 16);
}

__device__ __forceinline__ void async_load16(const void* g, void* l) {
    __builtin_amdgcn_global_load_lds(
        (const __attribute__((address_space(1))) unsigned int*)g,
        (__attribute__((address_space(3))) unsigned int*)l, 16, 0, 0);
}

// ---------------------------------------------------------------------------
// PREP1 (grid 256):
//   blk<128 : cast h->bf16 + hbar atomic partials (16 rows/blk)
//   128..255: G[h64+e, d] = sum_e' fu_W1[h,e,e'] * Wv[h64+e', d]  -> bf16.
//             (fu_W1 layer-1 "self" block collapsed into the GEMM1 weight;
//              HF never needs to be materialized or re-multiplied.)
//             Per block: head hh, 128-col chunk. Wv staged via LDS; fu_W1
//             read with wave-uniform addressing (scalar-load path, K$-cached).
// ---------------------------------------------------------------------------
__global__ __launch_bounds__(256) void k_prep1(const float* __restrict__ h,
                                               const float* __restrict__ Wv,
                                               const float* __restrict__ fu_W1,
                                               unsigned short* __restrict__ hbf,
                                               unsigned short* __restrict__ Gbf,
                                               float* __restrict__ hbar) {
    __shared__ float smem[4160];   // Wvs [64][65]
    int blk = blockIdx.x, tid = threadIdx.x;
    if (blk < 128) {
        int b = blk >> 6, chunk = blk & 63;
        int n0 = chunk * 16, d0 = tid * 4;
        const float* hb = h + (size_t)b * 1048576 + d0;
        unsigned short* ob = hbf + (size_t)b * 1048576 + d0;
        float4 sum = make_float4(0.f, 0.f, 0.f, 0.f);
#pragma unroll
        for (int i = 0; i < 16; ++i) {
            float4 v = *(const float4*)(hb + (size_t)(n0 + i) * 1024);
            sum.x += v.x; sum.y += v.y; sum.z += v.z; sum.w += v.w;
            *(ushort4*)(ob + (size_t)(n0 + i) * 1024) =
                make_ushort4(f2bf(v.x), f2bf(v.y), f2bf(v.z), f2bf(v.w));
        }
        float* hp = hbar + b * 1024 + d0;
        atomicAdd(hp + 0, sum.x * (1.f / 1024.f));
        atomicAdd(hp + 1, sum.y * (1.f / 1024.f));
        atomicAdd(hp + 2, sum.z * (1.f / 1024.f));
        atomicAdd(hp + 3, sum.w * (1.f / 1024.f));
    } else {
        int g = blk - 128;
        int hh = g >> 3, q = g & 7;
        int c0 = q * 128;
        int cl = tid & 63;
        int ebu = __builtin_amdgcn_readfirstlane(tid >> 6) * 16;  // wave-uniform
        const float* w1base = fu_W1 + (size_t)(hh * 64) * 192;
#pragma unroll
        for (int sc = 0; sc < 2; ++sc) {
            if (sc) __syncthreads();           // protect Wvs overwrite
#pragma unroll
            for (int i = 0; i < 16; ++i) {
                int idx = tid + i * 256;
                int r = idx >> 6, cc = idx & 63;
                smem[r * 65 + cc] =
                    Wv[(size_t)(hh * 64 + r) * 1024 + c0 + sc * 64 + cc];
            }
            __syncthreads();
            float acc[16];
#pragma unroll
            for (int e = 0; e < 16; ++e) acc[e] = 0.f;
            for (int ep = 0; ep < 64; ep += 4) {
                float wv0 = smem[(ep + 0) * 65 + cl];
                float wv1 = smem[(ep + 1) * 65 + cl];
                float wv2 = smem[(ep + 2) * 65 + cl];
                float wv3 = smem[(ep + 3) * 65 + cl];
#pragma unroll
                for (int e = 0; e < 16; ++e) {
                    const float* w1 = w1base + (size_t)(ebu + e) * 192 + ep;
                    acc[e] += w1[0] * wv0 + w1[1] * wv1 + w1[2] * wv2 + w1[3] * wv3;
                }
            }
            unsigned short* gp =
                Gbf + (size_t)(hh * 64 + ebu) * 1024 + c0 + sc * 64 + cl;
#pragma unroll
            for (int e = 0; e < 16; ++e) gp[(size_t)e * 1024] = f2bf(acc[e]);
        }
    }
}

// ---------------------------------------------------------------------------
// PREP2 (grid 288): blk<256 : M[e',h64+e] = sum_f Wo[e',h64+f]*fu_W2[h,f,e]
//                   (LDS-staged, coalesced; fused bias partial via atomics)
//                   256..287: cvec (per b,head): mf = Wv.hbar, c = b1+(W1b+W1c)mf
// ---------------------------------------------------------------------------
__global__ __launch_bounds__(256) void k_prep2(const float* __restrict__ Wo,
                                               const float* __restrict__ fu_W2,
                                               const float* __restrict__ fu_b2,
                                               const float* __restrict__ Wv,
                                               const float* __restrict__ fu_W1,
                                               const float* __restrict__ fu_b1,
                                               const float* __restrict__ hbar,
                                               unsigned short* __restrict__ Mbf,
                                               float* __restrict__ bias,
                                               float* __restrict__ cvec) {
    __shared__ float smem[8384];   // W2s[64][65] + Wos[64][65] + b2s[64]
    int blk = blockIdx.x, tid = threadIdx.x;
    if (blk < 256) {
        float* W2s = smem;               // [f][e] stride 65
        float* Wos = smem + 4160;        // [r][f] stride 65
        float* b2s = smem + 8320;
        int rc = blk >> 4, hh = blk & 15;
        int r0 = rc * 64;
#pragma unroll
        for (int i = 0; i < 16; ++i) {
            int idx = tid + i * 256;
            int f = idx >> 6, e = idx & 63;
            W2s[f * 65 + e] = fu_W2[hh * 4096 + idx];
            Wos[f * 65 + e] = Wo[(size_t)(r0 + f) * 1024 + hh * 64 + e];
        }
        if (tid < 64) b2s[tid] = fu_b2[hh * 64 + tid];
        __syncthreads();
        // each thread: 2 rows x 8 cols
        int ty = tid >> 3, tx = tid & 7;
        int r1 = 2 * ty, r2 = 2 * ty + 1, e0 = tx * 8;
        float acc0[8], acc1[8];
#pragma unroll
        for (int j = 0; j < 8; ++j) { acc0[j] = 0.f; acc1[j] = 0.f; }
        for (int f = 0; f < 64; ++f) {
            float a0 = Wos[r1 * 65 + f], a1 = Wos[r2 * 65 + f];
            const float* w2r = &W2s[f * 65 + e0];
#pragma unroll
            for (int j = 0; j < 8; ++j) {
                float b = w2r[j];
                acc0[j] += a0 * b;
                acc1[j] += a1 * b;
            }
        }
        unsigned short* m1 = Mbf + (size_t)(r0 + r1) * 1024 + hh * 64 + e0;
        unsigned short* m2 = Mbf + (size_t)(r0 + r2) * 1024 + hh * 64 + e0;
        *(ushort4*)(m1) = make_ushort4(f2bf(acc0[0]), f2bf(acc0[1]), f2bf(acc0[2]), f2bf(acc0[3]));
        *(ushort4*)(m1 + 4) = make_ushort4(f2bf(acc0[4]), f2bf(acc0[5]), f2bf(acc0[6]), f2bf(acc0[7]));
        *(ushort4*)(m2) = make_ushort4(f2bf(acc1[0]), f2bf(acc1[1]), f2bf(acc1[2]), f2bf(acc1[3]));
        *(ushort4*)(m2 + 4) = make_ushort4(f2bf(acc1[4]), f2bf(acc1[5]), f2bf(acc1[6]), f2bf(acc1[7]));
        // fused bias partial: bias[r0+r] += sum_f Wos[r][f]*b2s[f]
        if (tid < 64) {
            float p = 0.f;
#pragma unroll 8
            for (int f = 0; f < 64; ++f) p += Wos[tid * 65 + f] * b2s[f];
            atomicAdd(&bias[r0 + tid], p);
        }
    } else {
        float* psum = smem;              // [64][4]
        float* mf = smem + 256;          // [64]
        int blk2 = blk - 256;
        int b = blk2 >> 4, hh = blk2 & 15;
        int e = tid >> 2, sl = tid & 3;
        const float* wrow = Wv + (size_t)(hh * 64 + e) * 1024;
        const float* hb = hbar + b * 1024;
        float s = 0.f;
        int k0 = sl * 256;
        for (int k = k0; k < k0 + 256; ++k) s += wrow[k] * hb[k];
        psum[e * 4 + sl] = s;
        __syncthreads();
        if (tid < 64)
            mf[tid] = psum[tid * 4] + psum[tid * 4 + 1] + psum[tid * 4 + 2] + psum[tid * 4 + 3];
        __syncthreads();
        if (tid < 64) {
            const float* w1 = fu_W1 + (size_t)(hh * 64 + tid) * 192;
            float acc = fu_b1[hh * 64 + tid];
            for (int k = 0; k < 64; ++k) acc += (w1[64 + k] + w1[128 + k]) * mf[k];
            cvec[b * 1024 + hh * 64 + tid] = acc;
        }
    }
}

// ---------------------------------------------------------------------------
// GEMM: C = A[2048xK=1024] @ W[1024x1024]^T, bf16 MFMA.
// BM=32, BN=64, BK=64, 256 thr (4 waves, each 16x32 = 1x2 16x16 tiles).
// grid (64,16) = 1024 blocks = 4 blocks/CU.
// DOUBLE-BUFFERED LDS, ONE barrier/iter (best measured, R6).
// LDS: As[2][32][64]bf16 + Bs[2][64][64]bf16 = 24 KB, XOR-swizzle
//   byte(r,c) = r*128 + (((c>>3)^(r&7))<<4) + (c&7)*2  -> <=2-way conflicts.
// MODE 1: X = gelu(h @ G^T + c) — layer-1 pre-collapsed into G, so the
//         epilogue is just +c / GELU / bf16 store via LDS (swizzled).
// MODE 0: + bias -> fp32 out via LDS float4 stores; fused tail in block (0,0).
// ---------------------------------------------------------------------------
template <int MODE>
__global__ __launch_bounds__(256) void k_mm(const unsigned short* __restrict__ A,
                                            const unsigned short* __restrict__ Bw,
                                            void* __restrict__ CoutV,
                                            const float* __restrict__ cvec,
                                            const float* __restrict__ bias,
                                            const int* __restrict__ prev_idx,
                                            const float* __restrict__ chain_ratio) {
    __shared__ __align__(16) char smem[24576];
    // buffers: As0 @0, As1 @4096, Bs0 @8192, Bs1 @16384
    const int tid = threadIdx.x;
    const int w = tid >> 6, lane = tid & 63;
    const int rowBase = blockIdx.x * 32, colBase = blockIdx.y * 64;
    const int wmh = (w >> 1) * 16, wnh = (w & 1) * 32;
    const int lr = lane >> 3;                 // staging row within 8-row chunk
    const int ssrc = ((lane & 7) ^ lr) * 8;   // swizzled source k offset (elems)
    const int m_lane = lane & 15, quad = lane >> 4;

    if (MODE == 0 && blockIdx.x == 0 && blockIdx.y == 0) {
        // fused tail: targets + strength (closed-form: uniform softmax over a
        // broadcast scalar logit -> target 511 / chained prev_idx).
        float* out = (float*)CoutV;
        float cr = chain_ratio[0];
        float thr = floorf(1024.0f / (1.0f + expf(-cr)));
        float strength = 1.0f - logf(1.0f / 1024.0f + 1e-8f);
        for (int i = tid; i < 2048; i += 256) {
            int n = i & 1023;
            float fwd = 511.0f;
            if ((float)n >= thr) {
                int p = prev_idx[i];
                p = p < 0 ? 0 : (p > 1023 ? 1023 : p);
                fwd = (float)p;
            }
            out[2097152 + i] = fwd;
            out[2097152 + 2048 + i] = 511.0f;
            out[2097152 + 4096 + i] = strength;
        }
    }

    const unsigned short* Ag = A + (size_t)(rowBase + w * 8 + lr) * 1024 + ssrc;
    const unsigned short* Bg0 = Bw + (size_t)(colBase + w * 8 + lr) * 1024 + ssrc;
    const unsigned short* Bg1 = Bg0 + (size_t)32 * 1024;
    const int woff = w * 1024;                 // wave-uniform LDS staging offset

    f32x4 acc[2];
    acc[0] = (f32x4){0.f, 0.f, 0.f, 0.f};
    acc[1] = (f32x4){0.f, 0.f, 0.f, 0.f};

    // prologue: issue buf0 loads
    async_load16(Ag, smem + woff);
    async_load16(Bg0, smem + 8192 + woff);
    async_load16(Bg1, smem + 8192 + woff + 4096);

    for (int k0 = 0; k0 < 1024; k0 += 64) {
        const int cur = (k0 >> 6) & 1;
        char* Asc = smem + cur * 4096;
        char* Bsc = smem + 8192 + cur * 8192;
        __syncthreads();     // publishes buf cur (its loads issued 1 iter ago)
        if (k0 + 64 < 1024) {
            char* Asn = smem + (cur ^ 1) * 4096;
            char* Bsn = smem + 8192 + (cur ^ 1) * 8192;
            async_load16(Ag + k0 + 64, Asn + woff);
            async_load16(Bg0 + k0 + 64, Bsn + woff);
            async_load16(Bg1 + k0 + 64, Bsn + woff + 4096);
        }
#pragma unroll
        for (int kh = 0; kh < 2; ++kh) {
            const int seg = kh * 4 + quad;
            const int m = wmh + m_lane;
            bf16x8 af = *(const bf16x8*)(Asc + m * 128 + ((seg ^ (m & 7)) << 4));
#pragma unroll
            for (int nt = 0; nt < 2; ++nt) {
                int n = wnh + nt * 16 + m_lane;
                bf16x8 bfr = *(const bf16x8*)(Bsc + n * 128 + ((seg ^ (n & 7)) << 4));
                acc[nt] = __builtin_amdgcn_mfma_f32_16x16x32_bf16(af, bfr, acc[nt], 0, 0, 0);
            }
        }
    }

    char* As = smem;            // epilogue uses buffer-0 region
    if (MODE == 0) {
        float* out = (float*)CoutV;
        float* Os = (float*)smem;              // [32][68] fp32, 8704 B
        __syncthreads();                       // main-loop LDS reads done
#pragma unroll
        for (int nt = 0; nt < 2; ++nt) {
            int c = wnh + nt * 16 + m_lane;
            float bj = bias[colBase + c];
#pragma unroll
            for (int r4 = 0; r4 < 4; ++r4) {
                int r = wmh + quad * 4 + r4;
                Os[r * 68 + c] = acc[nt][r4] + bj;
            }
        }
        __syncthreads();
#pragma unroll
        for (int j = 0; j < 2; ++j) {
            int sidx = tid + j * 256;
            int r = sidx >> 4, sc = sidx & 15;
            float4 v = *(const float4*)&Os[r * 68 + sc * 4];
            *(float4*)&out[(size_t)(rowBase + r) * 1024 + colBase + sc * 4] = v;
        }
    } else {
        unsigned short* Xbf = (unsigned short*)CoutV;
        const int hh = blockIdx.y;             // head for this 64-col block
        const int b = rowBase >> 10;
        __syncthreads();                       // main-loop LDS reads done
        // X = gelu(acc + c) -> As (swizzled bf16 layout, <=2-way banks)
#pragma unroll
        for (int nt = 0; nt < 2; ++nt) {
            int c = wnh + nt * 16 + m_lane;
            float cadd = cvec[b * 1024 + hh * 64 + c];
#pragma unroll
            for (int r4 = 0; r4 < 4; ++r4) {
                int r = wmh + quad * 4 + r4;
                float t = acc[nt][r4] + cadd;
                t = 0.5f * t * (1.0f + erff(t * 0.70710678118654752f));
                *(unsigned short*)(As + r * 128 + (((c >> 3) ^ (r & 7)) << 4) +
                                   (c & 7) * 2) = f2bf(t);
            }
        }
        __syncthreads();
        // coalesced X store: 32 rows x 8 16B-segs = 256, 1 per thread
        int r = tid >> 3, s = tid & 7;
        float4 v = *(const float4*)(As + r * 128 + (((s) ^ (r & 7)) << 4));
        *(float4*)((char*)Xbf + ((size_t)(rowBase + r) * 1024 + colBase + s * 8) * 2) = v;
    }
}

// ---------------------------------------------------------------------------
extern "C" void kernel_launch(void* const* d_in, const int* in_sizes, int n_in,
                              void* d_out, int out_size, void* d_ws, size_t ws_size,
                              hipStream_t stream) {
    const float* h      = (const float*)d_in[0];
    const int*   prev   = (const int*)d_in[1];
    // d_in[2..9]: fw_*/bw_* encoder weights — provably unused (softmax over a
    // broadcast scalar logit is uniform 1/N regardless of the logit value).
    const float* Wv     = (const float*)d_in[10];
    const float* fu_W1  = (const float*)d_in[11];
    const float* fu_b1  = (const float*)d_in[12];
    const float* fu_W2  = (const float*)d_in[13];
    const float* fu_b2  = (const float*)d_in[14];
    const float* Wo     = (const float*)d_in[15];
    const float* cratio = (const float*)d_in[16];

    float* out = (float*)d_out;
    float* ws  = (float*)d_ws;
    unsigned short* hbf = (unsigned short*)(ws + OFF_HBF);
    unsigned short* Xbf = (unsigned short*)(ws + OFF_XBF);
    unsigned short* Gbf = (unsigned short*)(ws + OFF_GBF);
    unsigned short* Mbf = (unsigned short*)(ws + OFF_MBF);
    float* hbar = ws + OFF_HBAR;
    float* bias = ws + OFF_BIAS;
    float* cv   = ws + OFF_C;

    // zero hbar (2048) + bias (1024) — contiguous, one 12 KB memset
    hipMemsetAsync(hbar, 0, 3072 * sizeof(float), stream);
    // P1: h cast + hbar partials + G = fu_W1a (x) Wv collapse
    k_prep1<<<256, 256, 0, stream>>>(h, Wv, fu_W1, hbf, Gbf, hbar);
    // P2: M = Wo (x) fu_W2 collapse + bias + cvec
    k_prep2<<<288, 256, 0, stream>>>(Wo, fu_W2, fu_b2, Wv, fu_W1, fu_b1, hbar,
                                     Mbf, bias, cv);
    // GEMM1: X = gelu(h @ G^T + c)   (per-head MLP layer-1 folded into G)
    k_mm<1><<<dim3(64, 16), 256, 0, stream>>>(hbf, Gbf, Xbf, cv,
                                              nullptr, nullptr, nullptr);
    // GEMM2: out = X @ M^T + bias (fu_W2/Wo pre-collapsed into M); fused tail
    k_mm<0><<<dim3(64, 16), 256, 0, stream>>>(Xbf, Mbf, out, nullptr,
                                              bias, prev, cratio);
}

// Round 8
// 176.352 us; speedup vs baseline: 1.0561x; 1.0561x over previous
//
#include <hip/hip_runtime.h>
#include <hip/hip_bf16.h>

// Problem constants: D=1024, H=16, HD=64, B=2, N=1024, rows = B*N = 2048.

typedef __attribute__((ext_vector_type(8))) short bf16x8;
typedef __attribute__((ext_vector_type(4))) float f32x4;

// ws layout (float offsets).
#define OFF_HBF  0                 // h cast to bf16        [2048][1024] us
#define OFF_XBF  1048576           // X (gelu out) bf16     [2048][1024] us
#define OFF_WVBF 2097152           // Wv bf16               [1024][1024] us
#define OFF_MBF  2621440           // M = Wo(x)fu_W2 bf16   [1024][1024] us
#define OFF_W1A  3145728           // fu_W1[:,:,0:64] bf16  [16][64][64] us
#define OFF_HBAR 3178496           // mean of h over n [2][1024]   (memset w/ bias)
#define OFF_BIAS 3180544           // bias_vec = Wo @ fu_b2 [1024] (memset w/ hbar)
#define OFF_C    3181568           // c vec per (b,head,e) [2][1024]

__device__ __forceinline__ unsigned short f2bf(float f) {
    unsigned int u = __float_as_uint(f);
    u += 0x7fffu + ((u >> 16) & 1u);   // round-to-nearest-even
    return (unsigned short)(u >> 16);
}

__device__ __forceinline__ void async_load16(const void* g, void* l) {
    __builtin_amdgcn_global_load_lds(
        (const __attribute__((address_space(1))) unsigned int*)g,
        (__attribute__((address_space(3))) unsigned int*)l, 16, 0, 0);
}

// ---------------------------------------------------------------------------
// PREP1 (grid 1216): blk<128 : cast h->bf16 + hbar atomic partials (16 rows/blk)
//                    128..1151: cast Wv->bf16 (1024 elems/blk, float4)
//                    1152..1215: cast fu_W1[:,:,0:64] -> W1a bf16
// ---------------------------------------------------------------------------
__global__ __launch_bounds__(256) void k_prep1(const float* __restrict__ h,
                                               const float* __restrict__ Wv,
                                               const float* __restrict__ fu_W1,
                                               unsigned short* __restrict__ hbf,
                                               unsigned short* __restrict__ Wvbf,
                                               unsigned short* __restrict__ W1abf,
                                               float* __restrict__ hbar) {
    int blk = blockIdx.x, tid = threadIdx.x;
    if (blk < 128) {
        int b = blk >> 6, chunk = blk & 63;
        int n0 = chunk * 16, d0 = tid * 4;
        const float* hb = h + (size_t)b * 1048576 + d0;
        unsigned short* ob = hbf + (size_t)b * 1048576 + d0;
        float4 sum = make_float4(0.f, 0.f, 0.f, 0.f);
#pragma unroll
        for (int i = 0; i < 16; ++i) {
            float4 v = *(const float4*)(hb + (size_t)(n0 + i) * 1024);
            sum.x += v.x; sum.y += v.y; sum.z += v.z; sum.w += v.w;
            *(ushort4*)(ob + (size_t)(n0 + i) * 1024) =
                make_ushort4(f2bf(v.x), f2bf(v.y), f2bf(v.z), f2bf(v.w));
        }
        float* hp = hbar + b * 1024 + d0;
        atomicAdd(hp + 0, sum.x * (1.f / 1024.f));
        atomicAdd(hp + 1, sum.y * (1.f / 1024.f));
        atomicAdd(hp + 2, sum.z * (1.f / 1024.f));
        atomicAdd(hp + 3, sum.w * (1.f / 1024.f));
    } else if (blk < 1152) {
        int i0 = (blk - 128) * 1024 + tid * 4;
        float4 v = *(const float4*)(Wv + i0);
        *(ushort4*)(Wvbf + i0) =
            make_ushort4(f2bf(v.x), f2bf(v.y), f2bf(v.z), f2bf(v.w));
    } else {
        int blk2 = blk - 1152;                 // 0..63
        int hh = blk2 >> 2, q = blk2 & 3;
        int e = q * 16 + (tid >> 4);
        int k4 = (tid & 15) * 4;
        float4 v = *(const float4*)(fu_W1 + (size_t)(hh * 64 + e) * 192 + k4);
        *(ushort4*)(W1abf + hh * 4096 + e * 64 + k4) =
            make_ushort4(f2bf(v.x), f2bf(v.y), f2bf(v.z), f2bf(v.w));
    }
}

// ---------------------------------------------------------------------------
// PREP2 (grid 288): blk<256 : M[e',h64+e] = sum_f Wo[e',h64+f]*fu_W2[h,f,e]
//                   (LDS-staged, coalesced; fused bias partial via atomics)
//                   256..287: cvec (per b,head): mf = Wv.hbar, c = b1+(W1b+W1c)mf
// ---------------------------------------------------------------------------
__global__ __launch_bounds__(256) void k_prep2(const float* __restrict__ Wo,
                                               const float* __restrict__ fu_W2,
                                               const float* __restrict__ fu_b2,
                                               const float* __restrict__ Wv,
                                               const float* __restrict__ fu_W1,
                                               const float* __restrict__ fu_b1,
                                               const float* __restrict__ hbar,
                                               unsigned short* __restrict__ Mbf,
                                               float* __restrict__ bias,
                                               float* __restrict__ cvec) {
    __shared__ float smem[8384];   // W2s[64][65] + Wos[64][65] + b2s[64]
    int blk = blockIdx.x, tid = threadIdx.x;
    if (blk < 256) {
        float* W2s = smem;               // [f][e] stride 65
        float* Wos = smem + 4160;        // [r][f] stride 65
        float* b2s = smem + 8320;
        int rc = blk >> 4, hh = blk & 15;
        int r0 = rc * 64;
#pragma unroll
        for (int i = 0; i < 16; ++i) {
            int idx = tid + i * 256;
            int f = idx >> 6, e = idx & 63;
            W2s[f * 65 + e] = fu_W2[hh * 4096 + idx];
            Wos[f * 65 + e] = Wo[(size_t)(r0 + f) * 1024 + hh * 64 + e];
        }
        if (tid < 64) b2s[tid] = fu_b2[hh * 64 + tid];
        __syncthreads();
        // each thread: 2 rows x 8 cols
        int ty = tid >> 3, tx = tid & 7;
        int r1 = 2 * ty, r2 = 2 * ty + 1, e0 = tx * 8;
        float acc0[8], acc1[8];
#pragma unroll
        for (int j = 0; j < 8; ++j) { acc0[j] = 0.f; acc1[j] = 0.f; }
        for (int f = 0; f < 64; ++f) {
            float a0 = Wos[r1 * 65 + f], a1 = Wos[r2 * 65 + f];
            const float* w2r = &W2s[f * 65 + e0];
#pragma unroll
            for (int j = 0; j < 8; ++j) {
                float b = w2r[j];
                acc0[j] += a0 * b;
                acc1[j] += a1 * b;
            }
        }
        unsigned short* m1 = Mbf + (size_t)(r0 + r1) * 1024 + hh * 64 + e0;
        unsigned short* m2 = Mbf + (size_t)(r0 + r2) * 1024 + hh * 64 + e0;
        *(ushort4*)(m1) = make_ushort4(f2bf(acc0[0]), f2bf(acc0[1]), f2bf(acc0[2]), f2bf(acc0[3]));
        *(ushort4*)(m1 + 4) = make_ushort4(f2bf(acc0[4]), f2bf(acc0[5]), f2bf(acc0[6]), f2bf(acc0[7]));
        *(ushort4*)(m2) = make_ushort4(f2bf(acc1[0]), f2bf(acc1[1]), f2bf(acc1[2]), f2bf(acc1[3]));
        *(ushort4*)(m2 + 4) = make_ushort4(f2bf(acc1[4]), f2bf(acc1[5]), f2bf(acc1[6]), f2bf(acc1[7]));
        // fused bias partial: bias[r0+r] += sum_f Wos[r][f]*b2s[f]
        if (tid < 64) {
            float p = 0.f;
#pragma unroll 8
            for (int f = 0; f < 64; ++f) p += Wos[tid * 65 + f] * b2s[f];
            atomicAdd(&bias[r0 + tid], p);
        }
    } else {
        float* psum = smem;              // [64][4]
        float* mf = smem + 256;          // [64]
        int blk2 = blk - 256;
        int b = blk2 >> 4, hh = blk2 & 15;
        int e = tid >> 2, sl = tid & 3;
        const float* wrow = Wv + (size_t)(hh * 64 + e) * 1024;
        const float* hb = hbar + b * 1024;
        float s = 0.f;
        int k0 = sl * 256;
        for (int k = k0; k < k0 + 256; ++k) s += wrow[k] * hb[k];
        psum[e * 4 + sl] = s;
        __syncthreads();
        if (tid < 64)
            mf[tid] = psum[tid * 4] + psum[tid * 4 + 1] + psum[tid * 4 + 2] + psum[tid * 4 + 3];
        __syncthreads();
        if (tid < 64) {
            const float* w1 = fu_W1 + (size_t)(hh * 64 + tid) * 192;
            float acc = fu_b1[hh * 64 + tid];
            for (int k = 0; k < 64; ++k) acc += (w1[64 + k] + w1[128 + k]) * mf[k];
            cvec[b * 1024 + hh * 64 + tid] = acc;
        }
    }
}

// ---------------------------------------------------------------------------
// GEMM: C = A[2048xK=1024] @ W[1024x1024]^T, bf16 MFMA.
// BM=32, BN=64, BK=64, 256 thr (4 waves, each 16x32 = 1x2 16x16 tiles).
// grid (64,16) = 1024 blocks = 4 blocks/CU.
// DOUBLE-BUFFERED LDS, ONE barrier/iter: sync publishes buf `cur` (whose
// loads were issued a full compute-phase earlier -> near-zero vmcnt drain),
// then issue buf `next` loads, then compute on `cur`.
// LDS: As[2][32][64]bf16 (2x4K) + Bs[2][64][64]bf16 (2x8K) = 24 KB, XOR-swizzle
//   byte(r,c) = r*128 + (((c>>3)^(r&7))<<4) + (c&7)*2  -> <=2-way conflicts.
// MODE 1: epilogue = per-head 64x64 MLP (HF->LDS A-layout, W1a as B) + c +
//         exact GELU -> X bf16 (coalesced via LDS).
// MODE 0: + bias -> fp32 out via LDS float4 stores; fused tail in block (0,0).
// ---------------------------------------------------------------------------
template <int MODE>
__global__ __launch_bounds__(256) void k_mm(const unsigned short* __restrict__ A,
                                            const unsigned short* __restrict__ Bw,
                                            void* __restrict__ CoutV,
                                            const unsigned short* __restrict__ W1a,
                                            const float* __restrict__ cvec,
                                            const float* __restrict__ bias,
                                            const int* __restrict__ prev_idx,
                                            const float* __restrict__ chain_ratio) {
    __shared__ __align__(16) char smem[24576];
    // buffers: As0 @0, As1 @4096, Bs0 @8192, Bs1 @16384
    const int tid = threadIdx.x;
    const int w = tid >> 6, lane = tid & 63;
    const int rowBase = blockIdx.x * 32, colBase = blockIdx.y * 64;
    const int wmh = (w >> 1) * 16, wnh = (w & 1) * 32;
    const int lr = lane >> 3;                 // staging row within 8-row chunk
    const int ssrc = ((lane & 7) ^ lr) * 8;   // swizzled source k offset (elems)
    const int m_lane = lane & 15, quad = lane >> 4;

    if (MODE == 0 && blockIdx.x == 0 && blockIdx.y == 0) {
        // fused tail: targets + strength (closed-form: uniform softmax over a
        // broadcast scalar logit -> target 511 / chained prev_idx).
        float* out = (float*)CoutV;
        float cr = chain_ratio[0];
        float thr = floorf(1024.0f / (1.0f + expf(-cr)));
        float strength = 1.0f - logf(1.0f / 1024.0f + 1e-8f);
        for (int i = tid; i < 2048; i += 256) {
            int n = i & 1023;
            float fwd = 511.0f;
            if ((float)n >= thr) {
                int p = prev_idx[i];
                p = p < 0 ? 0 : (p > 1023 ? 1023 : p);
                fwd = (float)p;
            }
            out[2097152 + i] = fwd;
            out[2097152 + 2048 + i] = 511.0f;
            out[2097152 + 4096 + i] = strength;
        }
    }

    const unsigned short* Ag = A + (size_t)(rowBase + w * 8 + lr) * 1024 + ssrc;
    const unsigned short* Bg0 = Bw + (size_t)(colBase + w * 8 + lr) * 1024 + ssrc;
    const unsigned short* Bg1 = Bg0 + (size_t)32 * 1024;
    const int woff = w * 1024;                 // wave-uniform LDS staging offset

    f32x4 acc[2];
    acc[0] = (f32x4){0.f, 0.f, 0.f, 0.f};
    acc[1] = (f32x4){0.f, 0.f, 0.f, 0.f};

    // prologue: issue buf0 loads
    async_load16(Ag, smem + woff);
    async_load16(Bg0, smem + 8192 + woff);
    async_load16(Bg1, smem + 8192 + woff + 4096);

    for (int k0 = 0; k0 < 1024; k0 += 64) {
        const int cur = (k0 >> 6) & 1;
        char* Asc = smem + cur * 4096;
        char* Bsc = smem + 8192 + cur * 8192;
        __syncthreads();     // publishes buf cur (its loads issued 1 iter ago)
        if (k0 + 64 < 1024) {
            char* Asn = smem + (cur ^ 1) * 4096;
            char* Bsn = smem + 8192 + (cur ^ 1) * 8192;
            async_load16(Ag + k0 + 64, Asn + woff);
            async_load16(Bg0 + k0 + 64, Bsn + woff);
            async_load16(Bg1 + k0 + 64, Bsn + woff + 4096);
        }
#pragma unroll
        for (int kh = 0; kh < 2; ++kh) {
            const int seg = kh * 4 + quad;
            const int m = wmh + m_lane;
            bf16x8 af = *(const bf16x8*)(Asc + m * 128 + ((seg ^ (m & 7)) << 4));
#pragma unroll
            for (int nt = 0; nt < 2; ++nt) {
                int n = wnh + nt * 16 + m_lane;
                bf16x8 bfr = *(const bf16x8*)(Bsc + n * 128 + ((seg ^ (n & 7)) << 4));
                acc[nt] = __builtin_amdgcn_mfma_f32_16x16x32_bf16(af, bfr, acc[nt], 0, 0, 0);
            }
        }
    }

    char* As = smem;            // epilogue uses buffer-0 regions
    char* Bs = smem + 8192;
    if (MODE == 0) {
        float* out = (float*)CoutV;
        float* Os = (float*)smem;              // [32][68] fp32, 8704 B
        __syncthreads();                       // main-loop LDS reads done
#pragma unroll
        for (int nt = 0; nt < 2; ++nt) {
            int c = wnh + nt * 16 + m_lane;
            float bj = bias[colBase + c];
#pragma unroll
            for (int r4 = 0; r4 < 4; ++r4) {
                int r = wmh + quad * 4 + r4;
                Os[r * 68 + c] = acc[nt][r4] + bj;
            }
        }
        __syncthreads();
#pragma unroll
        for (int j = 0; j < 2; ++j) {
            int sidx = tid + j * 256;
            int r = sidx >> 4, sc = sidx & 15;
            float4 v = *(const float4*)&Os[r * 68 + sc * 4];
            *(float4*)&out[(size_t)(rowBase + r) * 1024 + colBase + sc * 4] = v;
        }
    } else {
        unsigned short* Xbf = (unsigned short*)CoutV;
        const int hh = blockIdx.y;             // head for this 64-col block
        __syncthreads();                       // main-loop LDS reads done
        // stage W1a head block [64 e_out][64 e_in] into Bs0 (swizzled, async)
        const unsigned short* Wg = W1a + hh * 4096 + (w * 8 + lr) * 64 + ssrc;
        async_load16(Wg, Bs + woff);
        async_load16(Wg + 32 * 64, Bs + woff + 4096);
        // write HF (bf16 of acc) into As0 in A-fragment (swizzled) layout
#pragma unroll
        for (int nt = 0; nt < 2; ++nt) {
            int c = wnh + nt * 16 + m_lane;
#pragma unroll
            for (int r4 = 0; r4 < 4; ++r4) {
                int r = wmh + quad * 4 + r4;
                *(unsigned short*)(As + r * 128 + (((c >> 3) ^ (r & 7)) << 4) +
                                   (c & 7) * 2) = f2bf(acc[nt][r4]);
            }
        }
        __syncthreads();                       // drains vmcnt -> W1a staged
        f32x4 acc2[2];
        acc2[0] = (f32x4){0.f, 0.f, 0.f, 0.f};
        acc2[1] = (f32x4){0.f, 0.f, 0.f, 0.f};
#pragma unroll
        for (int kh = 0; kh < 2; ++kh) {
            const int seg = kh * 4 + quad;
            const int m = wmh + m_lane;
            bf16x8 af = *(const bf16x8*)(As + m * 128 + ((seg ^ (m & 7)) << 4));
#pragma unroll
            for (int nt = 0; nt < 2; ++nt) {
                int n = wnh + nt * 16 + m_lane;
                bf16x8 bfr = *(const bf16x8*)(Bs + n * 128 + ((seg ^ (n & 7)) << 4));
                acc2[nt] = __builtin_amdgcn_mfma_f32_16x16x32_bf16(af, bfr, acc2[nt], 0, 0, 0);
            }
        }
        __syncthreads();                       // HF reads done; As reusable
        const int b = rowBase >> 10;
#pragma unroll
        for (int nt = 0; nt < 2; ++nt) {
            int c = wnh + nt * 16 + m_lane;
            float cadd = cvec[b * 1024 + hh * 64 + c];
#pragma unroll
            for (int r4 = 0; r4 < 4; ++r4) {
                int r = wmh + quad * 4 + r4;
                float t = acc2[nt][r4] + cadd;
                t = 0.5f * t * (1.0f + erff(t * 0.70710678118654752f));
                *(unsigned short*)(As + r * 128 + c * 2) = f2bf(t);  // plain layout
            }
        }
        __syncthreads();
        // coalesced X store: 32 rows x 8 16B-segs = 256, 1 per thread
        int r = tid >> 3, s = tid & 7;
        float4 v = *(const float4*)(As + r * 128 + s * 16);
        *(float4*)((char*)Xbf + ((size_t)(rowBase + r) * 1024 + colBase + s * 8) * 2) = v;
    }
}

// ---------------------------------------------------------------------------
extern "C" void kernel_launch(void* const* d_in, const int* in_sizes, int n_in,
                              void* d_out, int out_size, void* d_ws, size_t ws_size,
                              hipStream_t stream) {
    const float* h      = (const float*)d_in[0];
    const int*   prev   = (const int*)d_in[1];
    // d_in[2..9]: fw_*/bw_* encoder weights — provably unused (softmax over a
    // broadcast scalar logit is uniform 1/N regardless of the logit value).
    const float* Wv     = (const float*)d_in[10];
    const float* fu_W1  = (const float*)d_in[11];
    const float* fu_b1  = (const float*)d_in[12];
    const float* fu_W2  = (const float*)d_in[13];
    const float* fu_b2  = (const float*)d_in[14];
    const float* Wo     = (const float*)d_in[15];
    const float* cratio = (const float*)d_in[16];

    float* out = (float*)d_out;
    float* ws  = (float*)d_ws;
    unsigned short* hbf   = (unsigned short*)(ws + OFF_HBF);
    unsigned short* Xbf   = (unsigned short*)(ws + OFF_XBF);
    unsigned short* Wvbf  = (unsigned short*)(ws + OFF_WVBF);
    unsigned short* Mbf   = (unsigned short*)(ws + OFF_MBF);
    unsigned short* W1abf = (unsigned short*)(ws + OFF_W1A);
    float* hbar = ws + OFF_HBAR;
    float* bias = ws + OFF_BIAS;
    float* cv   = ws + OFF_C;

    // zero hbar (2048) + bias (1024) — contiguous, one 12 KB memset
    hipMemsetAsync(hbar, 0, 3072 * sizeof(float), stream);
    k_prep1<<<1216, 256, 0, stream>>>(h, Wv, fu_W1, hbf, Wvbf, W1abf, hbar);
    k_prep2<<<288, 256, 0, stream>>>(Wo, fu_W2, fu_b2, Wv, fu_W1, fu_b1, hbar,
                                     Mbf, bias, cv);
    // GEMM1: HF = h @ Wv^T (bf16 MFMA), fused per-head MLP layer1 + GELU -> X
    k_mm<1><<<dim3(64, 16), 256, 0, stream>>>(hbf, Wvbf, Xbf, W1abf, cv,
                                              nullptr, nullptr, nullptr);
    // GEMM2: out = X @ M^T + bias (fu_W2/Wo pre-collapsed into M); fused tail
    k_mm<0><<<dim3(64, 16), 256, 0, stream>>>(Xbf, Mbf, out, nullptr, nullptr,
                                              bias, prev, cratio);
}